// Round 4
// baseline (263.391 us; speedup 1.0000x reference)
//
#include <hip/hip_runtime.h>
#include <stdint.h>

#define DM   768
#define NH   12
#define HD   64
#define NB   4
#define SQL  2048
#define MM   (NB*SQL)      // 8192 rows
#define NQ   (3*DM)        // 2304
#define BHN  (NB*NH)       // 48

typedef __bf16 bf16x8 __attribute__((ext_vector_type(8)));
typedef float  f32x4  __attribute__((ext_vector_type(4)));
typedef float  f32x16 __attribute__((ext_vector_type(16)));
typedef unsigned int uint2_t __attribute__((ext_vector_type(2)));

static __device__ __forceinline__ uint16_t f2bf(float f) {
    union { float f; uint32_t u; } x; x.f = f;
    return (uint16_t)((x.u + 0x7FFFu + ((x.u >> 16) & 1u)) >> 16);
}

static __device__ __forceinline__ uint32_t cvtpk(float lo, float hi) {
    uint32_t r;
    asm volatile("v_cvt_pk_bf16_f32 %0, %1, %2" : "=v"(r) : "v"(lo), "v"(hi));
    return r;
}

static __device__ __forceinline__ uint2_t plswap(uint32_t x, uint32_t y) {
    return __builtin_amdgcn_permlane32_swap(x, y, false, false);
}

static __device__ __forceinline__ float swap_max(float v) {
    uint32_t u = __builtin_bit_cast(uint32_t, v);
    uint2_t r = plswap(u, u);
    return fmaxf(__builtin_bit_cast(float, r.x), __builtin_bit_cast(float, r.y));
}

static __device__ __forceinline__ float swap_sum(float v) {
    uint32_t u = __builtin_bit_cast(uint32_t, v);
    uint2_t r = plswap(u, u);
    return __builtin_bit_cast(float, r.x) + __builtin_bit_cast(float, r.y);
}

static __device__ __forceinline__ void gl_lds16(const void* g, void* l) {
    __builtin_amdgcn_global_load_lds(
        (__attribute__((address_space(1))) void*)g,
        (__attribute__((address_space(3))) void*)l, 16, 0, 0);
}

static __device__ __forceinline__ bf16x8 ldfrag(const uint16_t* p) {
    return *reinterpret_cast<const bf16x8*>(p);
}

// ---------------- fp32 -> bf16 cast ----------------
__global__ __launch_bounds__(256) void cast_k(const float* __restrict__ s,
                                              uint16_t* __restrict__ d, int n) {
    int i = (blockIdx.x * 256 + threadIdx.x) * 8;
    if (i >= n) return;
    float4 v0 = *reinterpret_cast<const float4*>(s + i);
    float4 v1 = *reinterpret_cast<const float4*>(s + i + 4);
    ushort4 o0, o1;
    o0.x = f2bf(v0.x); o0.y = f2bf(v0.y); o0.z = f2bf(v0.z); o0.w = f2bf(v0.w);
    o1.x = f2bf(v1.x); o1.y = f2bf(v1.y); o1.z = f2bf(v1.z); o1.w = f2bf(v1.w);
    *reinterpret_cast<ushort4*>(d + i)     = o0;
    *reinterpret_cast<ushort4*>(d + i + 4) = o1;
}

// ---------------- bf16 GEMM: C = A[M][768] * Bt[N][768]^T + bias ----------------
template<int EPI>
__global__ __launch_bounds__(256)
void gemm_bt(const uint16_t* __restrict__ A, const uint16_t* __restrict__ Bt,
             const float* __restrict__ bias,
             float* __restrict__ outf,
             uint16_t* __restrict__ qws, uint16_t* __restrict__ kws,
             uint16_t* __restrict__ vws)
{
    __shared__ __align__(16) uint16_t lA[128*64];
    __shared__ __align__(16) uint16_t lB[128*64];
    const int tid = threadIdx.x;
    const int wid = tid >> 6, lane = tid & 63;
    const int a = lane >> 4, c = lane & 15;
    const int bm = blockIdx.x, bn = blockIdx.y;
    const int wm = (wid >> 1) * 64, wn = (wid & 1) * 64;

    const f32x4 fz = {0.f, 0.f, 0.f, 0.f};
    f32x4 acc[4][4];
#pragma unroll
    for (int i = 0; i < 4; i++)
#pragma unroll
        for (int j = 0; j < 4; j++) acc[i][j] = fz;

    uint32_t aoff[4], boff[4], loff[4];
#pragma unroll
    for (int r = 0; r < 4; r++) {
        int p = r*256 + wid*64 + lane;
        int row = p >> 3, ch = p & 7;
        int sch = ch ^ (row & 7);
        aoff[r] = (uint32_t)(bm*128 + row)*768u + (uint32_t)sch*8u;
        boff[r] = (uint32_t)(bn*128 + row)*768u + (uint32_t)sch*8u;
        loff[r] = (uint32_t)(r*256 + wid*64)*8u;
    }

    for (int kt = 0; kt < 12; ++kt) {
        const uint16_t* Ak = A + kt*64;
        const uint16_t* Bk = Bt + kt*64;
#pragma unroll
        for (int r = 0; r < 4; r++) gl_lds16(Ak + aoff[r], lA + loff[r]);
#pragma unroll
        for (int r = 0; r < 4; r++) gl_lds16(Bk + boff[r], lB + loff[r]);
        __syncthreads();
#pragma unroll
        for (int kk = 0; kk < 2; kk++) {
            bf16x8 af[4], bfr[4];
#pragma unroll
            for (int mi = 0; mi < 4; mi++) {
                int row = wm + mi*16 + c;
                int cc = kk*4 + a;
                af[mi] = ldfrag(lA + row*64 + ((cc ^ (row & 7)) * 8));
            }
#pragma unroll
            for (int ni = 0; ni < 4; ni++) {
                int row = wn + ni*16 + c;
                int cc = kk*4 + a;
                bfr[ni] = ldfrag(lB + row*64 + ((cc ^ (row & 7)) * 8));
            }
#pragma unroll
            for (int mi = 0; mi < 4; mi++)
#pragma unroll
                for (int ni = 0; ni < 4; ni++)
                    acc[mi][ni] = __builtin_amdgcn_mfma_f32_16x16x32_bf16(
                        af[mi], bfr[ni], acc[mi][ni], 0, 0, 0);
        }
        __syncthreads();
    }

    // epilogue
#pragma unroll
    for (int mi = 0; mi < 4; mi++) {
#pragma unroll
        for (int ni = 0; ni < 4; ni++) {
            int n = bn*128 + wn + ni*16 + c;
            float bv = bias[n];
            int m0 = bm*128 + wm + mi*16 + a*4;
            if (EPI == 1) {
#pragma unroll
                for (int r = 0; r < 4; r++)
                    outf[(uint32_t)(m0 + r)*768u + n] = acc[mi][ni][r] + bv;
            } else {
                int sec = n / 768;           // uniform per block (768 = 6*128)
                int nn = n - sec*768;
                int h = nn >> 6, d = nn & 63;
                if (sec == 0) {
#pragma unroll
                    for (int r = 0; r < 4; r++) {
                        int m = m0 + r;
                        int b = m >> 11, s = m & 2047;
                        qws[((uint32_t)(b*NH + h)*SQL + s)*HD + d] =
                            f2bf((acc[mi][ni][r] + bv) * 0.18033688f);
                    }
                } else if (sec == 1) {
#pragma unroll
                    for (int r = 0; r < 4; r++) {
                        int m = m0 + r;
                        int b = m >> 11, s = m & 2047;
                        kws[((uint32_t)(b*NH + h)*SQL + s)*HD + d] =
                            f2bf(acc[mi][ni][r] + bv);
                    }
                } else {
                    int b = m0 >> 11, s0 = m0 & 2047;
                    ushort4 pk;
                    pk.x = f2bf(acc[mi][ni][0] + bv);
                    pk.y = f2bf(acc[mi][ni][1] + bv);
                    pk.z = f2bf(acc[mi][ni][2] + bv);
                    pk.w = f2bf(acc[mi][ni][3] + bv);
                    *reinterpret_cast<ushort4*>(
                        vws + ((uint32_t)(b*NH + h)*HD + d)*SQL + s0) = pk;
                }
            }
        }
    }
}

// ---------------- flash attention, swapped-operand 32x32, LDS-free ----------------
// Q,K: [BH][S][64] bf16 (Q pre-scaled by 0.125*log2e). Vt: [BH][64][S] bf16.
// O: [B][S][768] bf16. Block = 4 waves, 128 q-rows; KV tile = 64 keys.
// All K/V fragments loaded DIRECTLY global->VGPR (tiles are L1/L2-resident),
// no LDS, no barriers -> waves fully decoupled.
__global__ __launch_bounds__(256, 3)
void attn_k(const uint16_t* __restrict__ Q, const uint16_t* __restrict__ Kg,
            const uint16_t* __restrict__ Vt, uint16_t* __restrict__ O)
{
    const int tid = threadIdx.x, wid = tid >> 6, lane = tid & 63;
    const int ql = lane & 31, hi = lane >> 5;
    const int qt = blockIdx.x, bh = blockIdx.y;
    const uint16_t* Qb = Q  + (size_t)bh * SQL * HD;
    const uint16_t* Kb = Kg + (size_t)bh * SQL * HD;
    const uint16_t* Vb = Vt + (size_t)bh * HD * SQL;
    const int q0 = qt*128 + wid*32;

    // Q fragments (B-operand): qf[ks] = Q[q0+ql][ks*16 + hi*8 + j]
    bf16x8 qf[4];
#pragma unroll
    for (int ks = 0; ks < 4; ks++)
        qf[ks] = ldfrag(Qb + (uint32_t)(q0 + ql)*HD + ks*16 + hi*8);

    f32x16 oacc[2];
#pragma unroll
    for (int d0 = 0; d0 < 2; d0++)
#pragma unroll
        for (int r = 0; r < 16; r++) oacc[d0][r] = 0.f;
    float mr = -1e30f, lr = 0.f;

    // per-lane base pointers (fragment-direct addressing)
    const uint16_t* kp = Kb + (uint32_t)ql*HD  + hi*8;   // + t*4096 + kb*2048 + ks*16
    const uint16_t* vp = Vb + (uint32_t)ql*SQL + hi*8;   // + t*64 + d0*32*SQL + ks*16

    for (int t = 0; t < SQL/64; ++t) {
        // ---- K fragments (issued first; QK consumes) ----
        bf16x8 kf[2][4];
#pragma unroll
        for (int kb = 0; kb < 2; kb++)
#pragma unroll
            for (int ks = 0; ks < 4; ks++)
                kf[kb][ks] = ldfrag(kp + t*64*HD + kb*32*HD + ks*16);

        // ---- V fragments (issued second; PV consumes after softmax) ----
        bf16x8 vf[2][4];
#pragma unroll
        for (int d0 = 0; d0 < 2; d0++)
#pragma unroll
            for (int ks = 0; ks < 4; ks++)
                vf[d0][ks] = ldfrag(vp + t*64 + d0*32*SQL + ks*16);

        // ---- QK^T (swapped): sacc[kb] = K_tile(kb) . Q^T = S^T ----
        f32x16 sacc[2];
#pragma unroll
        for (int kb = 0; kb < 2; kb++)
#pragma unroll
            for (int r = 0; r < 16; r++) sacc[kb][r] = 0.f;
        __builtin_amdgcn_s_setprio(1);
#pragma unroll
        for (int kb = 0; kb < 2; kb++)
#pragma unroll
            for (int ks = 0; ks < 4; ks++)
                sacc[kb] = __builtin_amdgcn_mfma_f32_32x32x16_bf16(
                    kf[kb][ks], qf[ks], sacc[kb], 0, 0, 0);
        __builtin_amdgcn_s_setprio(0);

        // ---- online softmax, in-register, tree reductions, defer-max ----
        float tm[16];
#pragma unroll
        for (int r = 0; r < 16; r++) tm[r] = fmaxf(sacc[0][r], sacc[1][r]);
#pragma unroll
        for (int st = 8; st >= 1; st >>= 1)
#pragma unroll
            for (int r = 0; r < st; r++) tm[r] = fmaxf(tm[r], tm[r + st]);
        float pm = swap_max(tm[0]);

        if (!__all(pm <= mr + 8.0f)) {
            float mn = fmaxf(mr, pm);
            float al = exp2f(mr - mn);
            mr = mn;
            lr *= al;
#pragma unroll
            for (int d0 = 0; d0 < 2; d0++)
#pragma unroll
                for (int r = 0; r < 16; r++) oacc[d0][r] *= al;
        }

#pragma unroll
        for (int kb = 0; kb < 2; kb++)
#pragma unroll
            for (int r = 0; r < 16; r++)
                sacc[kb][r] = exp2f(sacc[kb][r] - mr);

        float ts[16];
#pragma unroll
        for (int r = 0; r < 16; r++) ts[r] = sacc[0][r] + sacc[1][r];
#pragma unroll
        for (int st = 8; st >= 1; st >>= 1)
#pragma unroll
            for (int r = 0; r < st; r++) ts[r] += ts[r + st];
        lr += swap_sum(ts[0]);

        // ---- P^T fragments in-register: cvt_pk + permlane32_swap ----
        bf16x8 pa[4];
#pragma unroll
        for (int kb = 0; kb < 2; kb++) {
            uint32_t a0 = cvtpk(sacc[kb][0],  sacc[kb][1]);
            uint32_t b0 = cvtpk(sacc[kb][4],  sacc[kb][5]);
            uint2_t  r0 = plswap(a0, b0);
            uint32_t a1 = cvtpk(sacc[kb][2],  sacc[kb][3]);
            uint32_t b1 = cvtpk(sacc[kb][6],  sacc[kb][7]);
            uint2_t  r1 = plswap(a1, b1);
            uint32_t a2 = cvtpk(sacc[kb][8],  sacc[kb][9]);
            uint32_t b2 = cvtpk(sacc[kb][12], sacc[kb][13]);
            uint2_t  r2 = plswap(a2, b2);
            uint32_t a3 = cvtpk(sacc[kb][10], sacc[kb][11]);
            uint32_t b3 = cvtpk(sacc[kb][14], sacc[kb][15]);
            uint2_t  r3 = plswap(a3, b3);
            union { uint32_t w[4]; bf16x8 v; } u0, u1;
            u0.w[0] = r0.x; u0.w[1] = r1.x; u0.w[2] = r0.y; u0.w[3] = r1.y;
            u1.w[0] = r2.x; u1.w[1] = r3.x; u1.w[2] = r2.y; u1.w[3] = r3.y;
            pa[kb*2]     = u0.v;
            pa[kb*2 + 1] = u1.v;
        }

        // ---- PV (swapped): oacc[d0] += V^T_tile(d0) . P^T ----
        __builtin_amdgcn_s_setprio(1);
#pragma unroll
        for (int ks = 0; ks < 4; ks++)
#pragma unroll
            for (int d0 = 0; d0 < 2; d0++)
                oacc[d0] = __builtin_amdgcn_mfma_f32_32x32x16_bf16(
                    vf[d0][ks], pa[ks], oacc[d0], 0, 0, 0);
        __builtin_amdgcn_s_setprio(0);
    }

    // ---- epilogue: O^T regs -> [B][S][768] bf16 ----
    const int b = bh / NH, h = bh % NH;
    float inv = 1.0f / lr;
    uint16_t* orow = O + ((size_t)b*SQL + q0 + ql)*768 + h*64;
#pragma unroll
    for (int d0 = 0; d0 < 2; d0++) {
#pragma unroll
        for (int g = 0; g < 4; g++) {
            uint2_t ww;
            ww.x = cvtpk(oacc[d0][g*4+0]*inv, oacc[d0][g*4+1]*inv);
            ww.y = cvtpk(oacc[d0][g*4+2]*inv, oacc[d0][g*4+3]*inv);
            *reinterpret_cast<uint2_t*>(orow + d0*32 + g*8 + hi*4) = ww;
        }
    }
}

// ---------------- launcher ----------------
extern "C" void kernel_launch(void* const* d_in, const int* in_sizes, int n_in,
                              void* d_out, int out_size, void* d_ws, size_t ws_size,
                              hipStream_t stream)
{
    const float* x      = (const float*)d_in[0];
    const float* w_qkv  = (const float*)d_in[1];
    const float* b_qkv  = (const float*)d_in[2];
    const float* w_proj = (const float*)d_in[3];
    const float* b_proj = (const float*)d_in[4];
    float* out = (float*)d_out;

    char* ws = (char*)d_ws;
    size_t off = 0;
    auto alloc = [&](size_t bytes) {
        char* p = ws + off;
        off += (bytes + 255) & ~(size_t)255;
        return p;
    };
    uint16_t* xb  = (uint16_t*)alloc((size_t)MM*DM*2);
    uint16_t* wqb = (uint16_t*)alloc((size_t)NQ*DM*2);
    uint16_t* wpb = (uint16_t*)alloc((size_t)DM*DM*2);
    uint16_t* qws = (uint16_t*)alloc((size_t)BHN*SQL*HD*2);
    uint16_t* kws = (uint16_t*)alloc((size_t)BHN*SQL*HD*2);
    uint16_t* vws = (uint16_t*)alloc((size_t)BHN*SQL*HD*2);
    uint16_t* aws = (uint16_t*)alloc((size_t)MM*DM*2);
    (void)in_sizes; (void)n_in; (void)out_size; (void)ws_size;

    cast_k<<<(MM*DM)/2048, 256, 0, stream>>>(x, xb, MM*DM);
    cast_k<<<(NQ*DM)/2048, 256, 0, stream>>>(w_qkv, wqb, NQ*DM);
    cast_k<<<(DM*DM)/2048, 256, 0, stream>>>(w_proj, wpb, DM*DM);

    gemm_bt<0><<<dim3(MM/128, NQ/128), 256, 0, stream>>>(
        xb, wqb, b_qkv, nullptr, qws, kws, vws);

    attn_k<<<dim3(SQL/128, BHN), 256, 0, stream>>>(qws, kws, vws, aws);

    gemm_bt<1><<<dim3(MM/128, DM/128), 256, 0, stream>>>(
        aws, wpb, b_proj, out, nullptr, nullptr, nullptr);
}

// Round 5
// 184.808 us; speedup vs baseline: 1.4252x; 1.4252x over previous
//
#include <hip/hip_runtime.h>
#include <stdint.h>

#define DM   768
#define NH   12
#define HD   64
#define NB   4
#define SQL  2048
#define MM   (NB*SQL)      // 8192 rows
#define NQ   (3*DM)        // 2304
#define BHN  (NB*NH)       // 48
#define NT   (SQL/64)      // 32 KV tiles

typedef __bf16 bf16x8 __attribute__((ext_vector_type(8)));
typedef float  f32x4  __attribute__((ext_vector_type(4)));
typedef float  f32x16 __attribute__((ext_vector_type(16)));
typedef unsigned int uint2_t __attribute__((ext_vector_type(2)));

static __device__ __forceinline__ uint16_t f2bf(float f) {
    union { float f; uint32_t u; } x; x.f = f;
    return (uint16_t)((x.u + 0x7FFFu + ((x.u >> 16) & 1u)) >> 16);
}

static __device__ __forceinline__ uint32_t cvtpk(float lo, float hi) {
    uint32_t r;
    asm volatile("v_cvt_pk_bf16_f32 %0, %1, %2" : "=v"(r) : "v"(lo), "v"(hi));
    return r;
}

static __device__ __forceinline__ uint2_t plswap(uint32_t x, uint32_t y) {
    return __builtin_amdgcn_permlane32_swap(x, y, false, false);
}

static __device__ __forceinline__ float swap_max(float v) {
    uint32_t u = __builtin_bit_cast(uint32_t, v);
    uint2_t r = plswap(u, u);
    return fmaxf(__builtin_bit_cast(float, r.x), __builtin_bit_cast(float, r.y));
}

static __device__ __forceinline__ float swap_sum(float v) {
    uint32_t u = __builtin_bit_cast(uint32_t, v);
    uint2_t r = plswap(u, u);
    return __builtin_bit_cast(float, r.x) + __builtin_bit_cast(float, r.y);
}

static __device__ __forceinline__ void gl_lds16(const void* g, void* l) {
    __builtin_amdgcn_global_load_lds(
        (__attribute__((address_space(1))) void*)g,
        (__attribute__((address_space(3))) void*)l, 16, 0, 0);
}

static __device__ __forceinline__ bf16x8 ldfrag(const uint16_t* p) {
    return *reinterpret_cast<const bf16x8*>(p);
}

// ---------------- fp32 -> bf16 cast ----------------
__global__ __launch_bounds__(256) void cast_k(const float* __restrict__ s,
                                              uint16_t* __restrict__ d, int n) {
    int i = (blockIdx.x * 256 + threadIdx.x) * 8;
    if (i >= n) return;
    float4 v0 = *reinterpret_cast<const float4*>(s + i);
    float4 v1 = *reinterpret_cast<const float4*>(s + i + 4);
    ushort4 o0, o1;
    o0.x = f2bf(v0.x); o0.y = f2bf(v0.y); o0.z = f2bf(v0.z); o0.w = f2bf(v0.w);
    o1.x = f2bf(v1.x); o1.y = f2bf(v1.y); o1.z = f2bf(v1.z); o1.w = f2bf(v1.w);
    *reinterpret_cast<ushort4*>(d + i)     = o0;
    *reinterpret_cast<ushort4*>(d + i + 4) = o1;
}

// ---------------- bf16 GEMM: C = A[M][768] * Bt[N][768]^T + bias ----------------
template<int EPI>
__global__ __launch_bounds__(256)
void gemm_bt(const uint16_t* __restrict__ A, const uint16_t* __restrict__ Bt,
             const float* __restrict__ bias,
             float* __restrict__ outf,
             uint16_t* __restrict__ qws, uint16_t* __restrict__ kws,
             uint16_t* __restrict__ vws)
{
    __shared__ __align__(16) uint16_t lA[128*64];
    __shared__ __align__(16) uint16_t lB[128*64];
    const int tid = threadIdx.x;
    const int wid = tid >> 6, lane = tid & 63;
    const int a = lane >> 4, c = lane & 15;
    const int bm = blockIdx.x, bn = blockIdx.y;
    const int wm = (wid >> 1) * 64, wn = (wid & 1) * 64;

    const f32x4 fz = {0.f, 0.f, 0.f, 0.f};
    f32x4 acc[4][4];
#pragma unroll
    for (int i = 0; i < 4; i++)
#pragma unroll
        for (int j = 0; j < 4; j++) acc[i][j] = fz;

    uint32_t aoff[4], boff[4], loff[4];
#pragma unroll
    for (int r = 0; r < 4; r++) {
        int p = r*256 + wid*64 + lane;
        int row = p >> 3, ch = p & 7;
        int sch = ch ^ (row & 7);
        aoff[r] = (uint32_t)(bm*128 + row)*768u + (uint32_t)sch*8u;
        boff[r] = (uint32_t)(bn*128 + row)*768u + (uint32_t)sch*8u;
        loff[r] = (uint32_t)(r*256 + wid*64)*8u;
    }

    for (int kt = 0; kt < 12; ++kt) {
        const uint16_t* Ak = A + kt*64;
        const uint16_t* Bk = Bt + kt*64;
#pragma unroll
        for (int r = 0; r < 4; r++) gl_lds16(Ak + aoff[r], lA + loff[r]);
#pragma unroll
        for (int r = 0; r < 4; r++) gl_lds16(Bk + boff[r], lB + loff[r]);
        __syncthreads();
#pragma unroll
        for (int kk = 0; kk < 2; kk++) {
            bf16x8 af[4], bfr[4];
#pragma unroll
            for (int mi = 0; mi < 4; mi++) {
                int row = wm + mi*16 + c;
                int cc = kk*4 + a;
                af[mi] = ldfrag(lA + row*64 + ((cc ^ (row & 7)) * 8));
            }
#pragma unroll
            for (int ni = 0; ni < 4; ni++) {
                int row = wn + ni*16 + c;
                int cc = kk*4 + a;
                bfr[ni] = ldfrag(lB + row*64 + ((cc ^ (row & 7)) * 8));
            }
#pragma unroll
            for (int mi = 0; mi < 4; mi++)
#pragma unroll
                for (int ni = 0; ni < 4; ni++)
                    acc[mi][ni] = __builtin_amdgcn_mfma_f32_16x16x32_bf16(
                        af[mi], bfr[ni], acc[mi][ni], 0, 0, 0);
        }
        __syncthreads();
    }

    // epilogue
#pragma unroll
    for (int mi = 0; mi < 4; mi++) {
#pragma unroll
        for (int ni = 0; ni < 4; ni++) {
            int n = bn*128 + wn + ni*16 + c;
            float bv = bias[n];
            int m0 = bm*128 + wm + mi*16 + a*4;
            if (EPI == 1) {
#pragma unroll
                for (int r = 0; r < 4; r++)
                    outf[(uint32_t)(m0 + r)*768u + n] = acc[mi][ni][r] + bv;
            } else {
                int sec = n / 768;           // uniform per block (768 = 6*128)
                int nn = n - sec*768;
                int h = nn >> 6, d = nn & 63;
                if (sec == 0) {
#pragma unroll
                    for (int r = 0; r < 4; r++) {
                        int m = m0 + r;
                        int b = m >> 11, s = m & 2047;
                        qws[((uint32_t)(b*NH + h)*SQL + s)*HD + d] =
                            f2bf((acc[mi][ni][r] + bv) * 0.18033688f);
                    }
                } else if (sec == 1) {
#pragma unroll
                    for (int r = 0; r < 4; r++) {
                        int m = m0 + r;
                        int b = m >> 11, s = m & 2047;
                        kws[((uint32_t)(b*NH + h)*SQL + s)*HD + d] =
                            f2bf(acc[mi][ni][r] + bv);
                    }
                } else {
                    int b = m0 >> 11, s0 = m0 & 2047;
                    ushort4 pk;
                    pk.x = f2bf(acc[mi][ni][0] + bv);
                    pk.y = f2bf(acc[mi][ni][1] + bv);
                    pk.z = f2bf(acc[mi][ni][2] + bv);
                    pk.w = f2bf(acc[mi][ni][3] + bv);
                    *reinterpret_cast<ushort4*>(
                        vws + ((uint32_t)(b*NH + h)*HD + d)*SQL + s0) = pk;
                }
            }
        }
    }
}

// ---------------- flash attention, swapped-operand 32x32, T15 2-tile pipeline ----
// Q,K: [BH][S][64] bf16 (Q pre-scaled by 0.125*log2e). Vt: [BH][64][S] bf16.
// O: [B][S][768] bf16. Block = 4 waves, 128 q-rows; KV tile = 64 keys.
// Per phase: QK MFMAs of tile t (MFMA pipe) overlap softmax of tile t-1 (VALU),
// then PV of tile t-1. Two named register states (rule #20: static indexing).
__global__ __launch_bounds__(256)
void attn_k(const uint16_t* __restrict__ Q, const uint16_t* __restrict__ Kg,
            const uint16_t* __restrict__ Vt, uint16_t* __restrict__ O)
{
    __shared__ __align__(16) uint16_t lK[2][64*64];
    __shared__ __align__(16) uint16_t lV[2][64*64];
    const int tid = threadIdx.x, wid = tid >> 6, lane = tid & 63;
    const int ql = lane & 31, hi = lane >> 5;
    const int qt = blockIdx.x, bh = blockIdx.y;
    const uint16_t* Qb = Q  + (size_t)bh * SQL * HD;
    const uint16_t* Kb = Kg + (size_t)bh * SQL * HD;
    const uint16_t* Vb = Vt + (size_t)bh * HD * SQL;
    const int q0 = qt*128 + wid*32;

    // Q fragments (B-operand): qf[ks] = Q[q0+ql][ks*16 + hi*8 + j]
    bf16x8 qf[4];
#pragma unroll
    for (int ks = 0; ks < 4; ks++)
        qf[ks] = ldfrag(Qb + (uint32_t)(q0 + ql)*HD + ks*16 + hi*8);

    f32x16 oacc[2];
#pragma unroll
    for (int d0 = 0; d0 < 2; d0++)
#pragma unroll
        for (int r = 0; r < 16; r++) oacc[d0][r] = 0.f;
    float mr = -1e30f, lr = 0.f;

    // staging offsets (pre-swizzled global source -> linear LDS dest)
    uint32_t koff[2], voff[2], loff[2];
#pragma unroll
    for (int r = 0; r < 2; r++) {
        int p = r*256 + wid*64 + lane;
        int row = p >> 3, ch = p & 7;
        int sch = ch ^ (row & 7);
        koff[r] = (uint32_t)row*HD  + (uint32_t)sch*8u;
        voff[r] = (uint32_t)row*SQL + (uint32_t)sch*8u;
        loff[r] = (uint32_t)p*8u;
    }

    auto STAGE = [&](int t, int b) {
#pragma unroll
        for (int r = 0; r < 2; r++) {
            gl_lds16(Kb + t*64*HD + koff[r], lK[b] + loff[r]);
            gl_lds16(Vb + t*64    + voff[r], lV[b] + loff[r]);
        }
    };

    auto QK = [&](int b, f32x16 (&s)[2]) {
#pragma unroll
        for (int kb = 0; kb < 2; kb++)
#pragma unroll
            for (int r = 0; r < 16; r++) s[kb][r] = 0.f;
        __builtin_amdgcn_s_setprio(1);
#pragma unroll
        for (int kb = 0; kb < 2; kb++)
#pragma unroll
            for (int ks = 0; ks < 4; ks++) {
                int row = kb*32 + ql;
                int c8 = ks*2 + hi;
                bf16x8 kf = ldfrag(lK[b] + row*64 + ((c8 ^ (row & 7)) * 8));
                s[kb] = __builtin_amdgcn_mfma_f32_32x32x16_bf16(
                    kf, qf[ks], s[kb], 0, 0, 0);
            }
        __builtin_amdgcn_s_setprio(0);
    };

    auto LDV = [&](int b, bf16x8 (&v)[2][4]) {
#pragma unroll
        for (int d0 = 0; d0 < 2; d0++)
#pragma unroll
            for (int ks = 0; ks < 4; ks++) {
                int row = d0*32 + ql;
                int c8 = ks*2 + hi;
                v[d0][ks] = ldfrag(lV[b] + row*64 + ((c8 ^ (row & 7)) * 8));
            }
    };

    // softmax (tile t-1) + pack + PV (tile t-1)
    auto SMPV = [&](f32x16 (&s)[2], bf16x8 (&v)[2][4]) {
        float tm[16];
#pragma unroll
        for (int r = 0; r < 16; r++) tm[r] = fmaxf(s[0][r], s[1][r]);
#pragma unroll
        for (int st = 8; st >= 1; st >>= 1)
#pragma unroll
            for (int r = 0; r < st; r++) tm[r] = fmaxf(tm[r], tm[r + st]);
        float pm = swap_max(tm[0]);

        if (!__all(pm <= mr + 8.0f)) {
            float mn = fmaxf(mr, pm);
            float al = exp2f(mr - mn);
            mr = mn;
            lr *= al;
#pragma unroll
            for (int d0 = 0; d0 < 2; d0++)
#pragma unroll
                for (int r = 0; r < 16; r++) oacc[d0][r] *= al;
        }

#pragma unroll
        for (int kb = 0; kb < 2; kb++)
#pragma unroll
            for (int r = 0; r < 16; r++)
                s[kb][r] = exp2f(s[kb][r] - mr);

        float ts[16];
#pragma unroll
        for (int r = 0; r < 16; r++) ts[r] = s[0][r] + s[1][r];
#pragma unroll
        for (int st = 8; st >= 1; st >>= 1)
#pragma unroll
            for (int r = 0; r < st; r++) ts[r] += ts[r + st];
        lr += swap_sum(ts[0]);

        bf16x8 pa[4];
#pragma unroll
        for (int kb = 0; kb < 2; kb++) {
            uint32_t a0 = cvtpk(s[kb][0],  s[kb][1]);
            uint32_t b0 = cvtpk(s[kb][4],  s[kb][5]);
            uint2_t  r0 = plswap(a0, b0);
            uint32_t a1 = cvtpk(s[kb][2],  s[kb][3]);
            uint32_t b1 = cvtpk(s[kb][6],  s[kb][7]);
            uint2_t  r1 = plswap(a1, b1);
            uint32_t a2 = cvtpk(s[kb][8],  s[kb][9]);
            uint32_t b2 = cvtpk(s[kb][12], s[kb][13]);
            uint2_t  r2 = plswap(a2, b2);
            uint32_t a3 = cvtpk(s[kb][10], s[kb][11]);
            uint32_t b3 = cvtpk(s[kb][14], s[kb][15]);
            uint2_t  r3 = plswap(a3, b3);
            union { uint32_t w[4]; bf16x8 v; } u0, u1;
            u0.w[0] = r0.x; u0.w[1] = r1.x; u0.w[2] = r0.y; u0.w[3] = r1.y;
            u1.w[0] = r2.x; u1.w[1] = r3.x; u1.w[2] = r2.y; u1.w[3] = r3.y;
            pa[kb*2]     = u0.v;
            pa[kb*2 + 1] = u1.v;
        }

        __builtin_amdgcn_s_setprio(1);
#pragma unroll
        for (int ks = 0; ks < 4; ks++)
#pragma unroll
            for (int d0 = 0; d0 < 2; d0++)
                oacc[d0] = __builtin_amdgcn_mfma_f32_32x32x16_bf16(
                    v[d0][ks], pa[ks], oacc[d0], 0, 0, 0);
        __builtin_amdgcn_s_setprio(0);
    };

    f32x16 sA[2], sB[2];
    bf16x8 vA[2][4], vB[2][4];

    // prologue: stage tile 0, then peel tile 0 (QK only)
    STAGE(0, 0);
    __syncthreads();
    STAGE(1, 1);
    QK(0, sA);
    LDV(0, vA);
    __syncthreads();

    // pairs: tiles (1,2), (3,4), ..., (29,30)
    for (int p = 1; p <= NT - 3; p += 2) {
        // tile p (odd -> buf1): QK(p) overlaps softmax+PV of tile p-1
        QK(1, sB);
        STAGE(p + 1, 0);
        SMPV(sA, vA);
        LDV(1, vB);
        __syncthreads();
        // tile p+1 (even -> buf0)
        QK(0, sA);
        STAGE(p + 2, 1);
        SMPV(sB, vB);
        LDV(0, vA);
        __syncthreads();
    }

    // tail: tile 31 (buf1), then drain both states
    QK(1, sB);
    SMPV(sA, vA);
    LDV(1, vB);
    SMPV(sB, vB);

    // ---- epilogue: O^T regs -> [B][S][768] bf16 ----
    const int b = bh / NH, h = bh % NH;
    float inv = 1.0f / lr;
    uint16_t* orow = O + ((size_t)b*SQL + q0 + ql)*768 + h*64;
#pragma unroll
    for (int d0 = 0; d0 < 2; d0++) {
#pragma unroll
        for (int g = 0; g < 4; g++) {
            uint2_t ww;
            ww.x = cvtpk(oacc[d0][g*4+0]*inv, oacc[d0][g*4+1]*inv);
            ww.y = cvtpk(oacc[d0][g*4+2]*inv, oacc[d0][g*4+3]*inv);
            *reinterpret_cast<uint2_t*>(orow + d0*32 + g*8 + hi*4) = ww;
        }
    }
}

// ---------------- launcher ----------------
extern "C" void kernel_launch(void* const* d_in, const int* in_sizes, int n_in,
                              void* d_out, int out_size, void* d_ws, size_t ws_size,
                              hipStream_t stream)
{
    const float* x      = (const float*)d_in[0];
    const float* w_qkv  = (const float*)d_in[1];
    const float* b_qkv  = (const float*)d_in[2];
    const float* w_proj = (const float*)d_in[3];
    const float* b_proj = (const float*)d_in[4];
    float* out = (float*)d_out;

    char* ws = (char*)d_ws;
    size_t off = 0;
    auto alloc = [&](size_t bytes) {
        char* p = ws + off;
        off += (bytes + 255) & ~(size_t)255;
        return p;
    };
    uint16_t* xb  = (uint16_t*)alloc((size_t)MM*DM*2);
    uint16_t* wqb = (uint16_t*)alloc((size_t)NQ*DM*2);
    uint16_t* wpb = (uint16_t*)alloc((size_t)DM*DM*2);
    uint16_t* qws = (uint16_t*)alloc((size_t)BHN*SQL*HD*2);
    uint16_t* kws = (uint16_t*)alloc((size_t)BHN*SQL*HD*2);
    uint16_t* vws = (uint16_t*)alloc((size_t)BHN*SQL*HD*2);
    uint16_t* aws = (uint16_t*)alloc((size_t)MM*DM*2);
    (void)in_sizes; (void)n_in; (void)out_size; (void)ws_size;

    cast_k<<<(MM*DM)/2048, 256, 0, stream>>>(x, xb, MM*DM);
    cast_k<<<(NQ*DM)/2048, 256, 0, stream>>>(w_qkv, wqb, NQ*DM);
    cast_k<<<(DM*DM)/2048, 256, 0, stream>>>(w_proj, wpb, DM*DM);

    gemm_bt<0><<<dim3(MM/128, NQ/128), 256, 0, stream>>>(
        xb, wqb, b_qkv, nullptr, qws, kws, vws);

    attn_k<<<dim3(SQL/128, BHN), 256, 0, stream>>>(qws, kws, vws, aws);

    gemm_bt<1><<<dim3(MM/128, DM/128), 256, 0, stream>>>(
        aws, wpb, b_proj, out, nullptr, nullptr, nullptr);
}